// Round 6
// baseline (160.566 us; speedup 1.0000x reference)
//
#include <hip/hip_runtime.h>

#define B_ 8
#define EH_ 768
#define T_ 512
#define PH_ 320
#define U_ 128
#define JH_ 320
#define C_ 34
#define LDP 328       // LDS row stride in halfs (656 B -> 4-bank row offset, free 2-way)

typedef _Float16 f16x8 __attribute__((ext_vector_type(8)));
typedef _Float16 f16x4 __attribute__((ext_vector_type(4)));
typedef float f32x4 __attribute__((ext_vector_type(4)));

// relu(a+b) on 8 packed halves: v_pk_add_f16 + v_pk_max_f16
static __device__ __forceinline__ f16x8 relu_sum8(f16x8 a, f16x8 b) {
    f16x8 s = a + b;
    f16x8 z = (f16x8)(_Float16)0.f;
    return __builtin_elementwise_max(s, z);
}

// ---------------------------------------------------------------------------
// Fused prep: transpose+cvt enc/dec (b,H,N)f32 -> (b,N,H)f16; cvt weights;
// W_out padded to 48 rows (zeros c>=34).
//   enc blocks 3072, dec blocks 320, weight blocks ceil(363520/256)=1420
// ---------------------------------------------------------------------------
__global__ __launch_bounds__(256) void prep_kernel(
    const float* __restrict__ enc, const float* __restrict__ dec,
    const float* __restrict__ Wenc, const float* __restrict__ Wpred,
    const float* __restrict__ Wout,
    _Float16* __restrict__ enc_t, _Float16* __restrict__ dec_t,
    _Float16* __restrict__ wenc, _Float16* __restrict__ wpred,
    _Float16* __restrict__ wout48)
{
    __shared__ _Float16 tile[32][36];
    const int NE = 16 * 24 * B_;
    const int ND = 4 * 10 * B_;
    const int tid = threadIdx.x;
    int bid = blockIdx.x;

    if (bid < NE + ND) {
        const float* src; _Float16* dst; int H, N, n0, h0, b;
        if (bid < NE) {
            src = enc; dst = enc_t; H = EH_; N = T_;
            n0 = (bid % 16) * 32; h0 = ((bid / 16) % 24) * 32; b = bid / (16 * 24);
        } else {
            int i = bid - NE;
            src = dec; dst = dec_t; H = PH_; N = U_;
            n0 = (i % 4) * 32; h0 = ((i / 4) % 10) * 32; b = i / 40;
        }
        const int tx = tid & 7, ty = tid >> 3;
        float4 v = *(const float4*)&src[((size_t)b * H + h0 + ty) * N + n0 + tx * 4];
        f16x4 t;
        t[0] = (_Float16)v.x; t[1] = (_Float16)v.y; t[2] = (_Float16)v.z; t[3] = (_Float16)v.w;
        *(f16x4*)&tile[ty][tx * 4] = t;
        __syncthreads();
        f16x4 o;
        o[0] = tile[tx * 4 + 0][ty];
        o[1] = tile[tx * 4 + 1][ty];
        o[2] = tile[tx * 4 + 2][ty];
        o[3] = tile[tx * 4 + 3][ty];
        *(f16x4*)&dst[((size_t)b * N + n0 + ty) * H + h0 + tx * 4] = o;
    } else {
        const int t1 = JH_ * EH_, t2 = JH_ * PH_, t3 = 48 * JH_;
        int i = (bid - NE - ND) * 256 + tid;
        if (i < t1)                wenc[i] = (_Float16)Wenc[i];
        else if (i < t1 + t2)      wpred[i - t1] = (_Float16)Wpred[i - t1];
        else if (i < t1 + t2 + t3) {
            int k = i - t1 - t2;
            int c = k / JH_;
            wout48[k] = (c < C_) ? (_Float16)Wout[k] : (_Float16)0.f;
        }
    }
}

// ---------------------------------------------------------------------------
// Fused projections (e and p): dst[b,n,j] = bias[j] + sum_h src_t[b,n,h]*W[j,h]
// One wave = 32n x 32j tile; 4 b128 loads : 4 MFMA per k-step; no barriers.
//   e waves: (T/32)*(JH/32)*B = 1280 ; p waves: (U/32)*(JH/32)*B = 320
// grid 400 x 256 (4 waves/block)
// ---------------------------------------------------------------------------
__global__ __launch_bounds__(256) void proj_kernel(
    const _Float16* __restrict__ enc_t, const _Float16* __restrict__ dec_t,
    const _Float16* __restrict__ wenc, const _Float16* __restrict__ wpred,
    const float* __restrict__ b_enc, const float* __restrict__ b_pred,
    _Float16* __restrict__ e_f, _Float16* __restrict__ p_f)
{
    const int tid = threadIdx.x;
    const int wave = tid >> 6, lane = tid & 63;
    const int lrow = lane & 15, quad = lane >> 4;

    int wid = blockIdx.x * 4 + wave;
    const int We = (T_ / 32) * (JH_ / 32) * B_;
    const _Float16 *src, *W; const float* bias; _Float16* dst; int H, N, ntn;
    if (wid < We) { src = enc_t; W = wenc;  bias = b_enc;  dst = e_f; H = EH_; N = T_; ntn = T_ / 32; }
    else { wid -= We; src = dec_t; W = wpred; bias = b_pred; dst = p_f; H = PH_; N = U_; ntn = U_ / 32; }

    const int nt = wid % ntn; int r = wid / ntn;
    const int jt = r % (JH_ / 32); const int b = r / (JH_ / 32);
    const int n0 = nt * 32, j0 = jt * 32;

    const _Float16* a0p = src + ((size_t)b * N + n0 + lrow) * H + quad * 8;
    const _Float16* a1p = a0p + (size_t)16 * H;
    const _Float16* w0p = W + (size_t)(j0 + lrow) * H + quad * 8;
    const _Float16* w1p = w0p + (size_t)16 * H;

    f32x4 acc00 = {0.f,0.f,0.f,0.f}, acc01 = {0.f,0.f,0.f,0.f};
    f32x4 acc10 = {0.f,0.f,0.f,0.f}, acc11 = {0.f,0.f,0.f,0.f};

#pragma unroll 2
    for (int k = 0; k < H; k += 32) {
        f16x8 a0 = *(const f16x8*)(a0p + k);
        f16x8 a1 = *(const f16x8*)(a1p + k);
        f16x8 w0 = *(const f16x8*)(w0p + k);
        f16x8 w1 = *(const f16x8*)(w1p + k);
        acc00 = __builtin_amdgcn_mfma_f32_16x16x32_f16(w0, a0, acc00, 0, 0, 0);
        acc01 = __builtin_amdgcn_mfma_f32_16x16x32_f16(w0, a1, acc01, 0, 0, 0);
        acc10 = __builtin_amdgcn_mfma_f32_16x16x32_f16(w1, a0, acc10, 0, 0, 0);
        acc11 = __builtin_amdgcn_mfma_f32_16x16x32_f16(w1, a1, acc11, 0, 0, 0);
    }

    // D: row = j = jt2*16 + quad*4 + i, col = n = nt2*16 + lrow
#pragma unroll
    for (int jt2 = 0; jt2 < 2; ++jt2) {
        const float4 bj = *(const float4*)&bias[j0 + jt2 * 16 + quad * 4];
#pragma unroll
        for (int nt2 = 0; nt2 < 2; ++nt2) {
            const f32x4 ac = jt2 ? (nt2 ? acc11 : acc10) : (nt2 ? acc01 : acc00);
            f16x4 o;
            o[0] = (_Float16)(ac[0] + bj.x);
            o[1] = (_Float16)(ac[1] + bj.y);
            o[2] = (_Float16)(ac[2] + bj.z);
            o[3] = (_Float16)(ac[3] + bj.w);
            const int n = n0 + nt2 * 16 + lrow;
            *(f16x4*)&dst[((size_t)b * N + n) * JH_ + j0 + jt2 * 16 + quad * 4] = o;
        }
    }
}

// ---------------------------------------------------------------------------
// Fused joint: logits = relu(e[t]+p[u]) @ W_out^T + b_out, log_softmax (C=34)
// grid (T/8, U/32, B), block 256. Tile: 8t x 32u x 48c; wave = 4t x 16u.
// LDS holds ONLY p (32 rows) + e (8 rows) = 26.2 KB -> 4 blocks/CU (VGPR-capped).
// W fragments stream from global wout48 (48x320, zero-padded) -> L1-resident.
// ---------------------------------------------------------------------------
__global__ __launch_bounds__(256, 4) void joint_kernel(
    const _Float16* __restrict__ e_f, const _Float16* __restrict__ p_f,
    const _Float16* __restrict__ wout48, const float* __restrict__ b_out,
    float* __restrict__ out)
{
    __shared__ alignas(16) _Float16 lds[40 * LDP];

    const int tid = threadIdx.x;
    const int t0 = blockIdx.x * 8;
    const int u0 = blockIdx.y * 32;
    const int b  = blockIdx.z;

    {
        const uint4* sp = (const uint4*)(p_f + ((size_t)b * U_ + u0) * JH_);
        for (int i = tid; i < 32 * 40; i += 256) {
            int rr = i / 40, k8 = i % 40;
            *(uint4*)&lds[rr * LDP + k8 * 8] = sp[i];
        }
        const uint4* se = (const uint4*)(e_f + ((size_t)b * T_ + t0) * JH_);
        for (int i = tid; i < 8 * 40; i += 256) {
            int rr = i / 40, k8 = i % 40;
            *(uint4*)&lds[(32 + rr) * LDP + k8 * 8] = se[i];
        }
    }
    __syncthreads();

    const int lane = tid & 63, wave = tid >> 6;
    const int lrow = lane & 15, quad = lane >> 4;
    const int lk = quad * 8;
    const int urow  = (wave & 1) * 16 + lrow;        // p row in LDS
    const int tbase = 32 + (wave >> 1) * 4;          // first e row for this wave

    const _Float16* w0p = wout48 + (size_t)lrow * JH_ + lk;
    const _Float16* w1p = w0p + (size_t)16 * JH_;
    const _Float16* w2p = w0p + (size_t)32 * JH_;

    f32x4 acc[4][3];
#pragma unroll
    for (int tt = 0; tt < 4; ++tt)
#pragma unroll
        for (int c = 0; c < 3; ++c) acc[tt][c] = (f32x4){0.f, 0.f, 0.f, 0.f};

#pragma unroll 2
    for (int kk = 0; kk < 10; ++kk) {
        const int k = kk * 32;
        f16x8 w0 = *(const f16x8*)(w0p + k);
        f16x8 w1 = *(const f16x8*)(w1p + k);
        f16x8 w2 = *(const f16x8*)(w2p + k);
        f16x8 pv = *(const f16x8*)&lds[urow * LDP + lk + k];
#pragma unroll
        for (int tt = 0; tt < 4; ++tt) {
            f16x8 ev = *(const f16x8*)&lds[(tbase + tt) * LDP + lk + k];
            f16x8 h = relu_sum8(pv, ev);
            acc[tt][0] = __builtin_amdgcn_mfma_f32_16x16x32_f16(w0, h, acc[tt][0], 0, 0, 0);
            acc[tt][1] = __builtin_amdgcn_mfma_f32_16x16x32_f16(w1, h, acc[tt][1], 0, 0, 0);
            acc[tt][2] = __builtin_amdgcn_mfma_f32_16x16x32_f16(w2, h, acc[tt][2], 0, 0, 0);
        }
    }

    // D: row = c = nt*16 + quad*4 + i, col = u = lane&15
    const float4 bq0 = *(const float4*)&b_out[quad * 4];
    const float4 bq1 = *(const float4*)&b_out[16 + quad * 4];
    const bool q0 = (quad == 0);
    float b2x = 0.f, b2y = 0.f;
    if (q0) { b2x = b_out[32]; b2y = b_out[33]; }

    const int u = u0 + (wave & 1) * 16 + lrow;
#pragma unroll
    for (int tt = 0; tt < 4; ++tt) {
        float v0[4], v1[4];
        v0[0] = acc[tt][0][0] + bq0.x; v0[1] = acc[tt][0][1] + bq0.y;
        v0[2] = acc[tt][0][2] + bq0.z; v0[3] = acc[tt][0][3] + bq0.w;
        v1[0] = acc[tt][1][0] + bq1.x; v1[1] = acc[tt][1][1] + bq1.y;
        v1[2] = acc[tt][1][2] + bq1.z; v1[3] = acc[tt][1][3] + bq1.w;
        float v2x = q0 ? (acc[tt][2][0] + b2x) : -INFINITY;
        float v2y = q0 ? (acc[tt][2][1] + b2y) : -INFINITY;

        float m = fmaxf(fmaxf(fmaxf(v0[0], v0[1]), fmaxf(v0[2], v0[3])),
                        fmaxf(fmaxf(v1[0], v1[1]), fmaxf(v1[2], v1[3])));
        m = fmaxf(m, fmaxf(v2x, v2y));
        m = fmaxf(m, __shfl_xor(m, 16));
        m = fmaxf(m, __shfl_xor(m, 32));

        float s = __expf(v0[0] - m) + __expf(v0[1] - m) + __expf(v0[2] - m) + __expf(v0[3] - m)
                + __expf(v1[0] - m) + __expf(v1[1] - m) + __expf(v1[2] - m) + __expf(v1[3] - m);
        if (q0) s += __expf(v2x - m) + __expf(v2y - m);
        s += __shfl_xor(s, 16);
        s += __shfl_xor(s, 32);
        const float lse = m + __logf(s);

        const int t = t0 + (wave >> 1) * 4 + tt;
        float* po = out + (((size_t)b * T_ + t) * U_ + u) * C_;
        *(float2*)&po[quad * 4]          = make_float2(v0[0] - lse, v0[1] - lse);
        *(float2*)&po[quad * 4 + 2]      = make_float2(v0[2] - lse, v0[3] - lse);
        *(float2*)&po[16 + quad * 4]     = make_float2(v1[0] - lse, v1[1] - lse);
        *(float2*)&po[16 + quad * 4 + 2] = make_float2(v1[2] - lse, v1[3] - lse);
        if (q0) *(float2*)&po[32]        = make_float2(v2x - lse, v2y - lse);
    }
}

extern "C" void kernel_launch(void* const* d_in, const int* in_sizes, int n_in,
                              void* d_out, int out_size, void* d_ws, size_t ws_size,
                              hipStream_t stream) {
    const float* enc    = (const float*)d_in[0];
    const float* dec    = (const float*)d_in[1];
    const float* W_enc  = (const float*)d_in[2];
    const float* b_enc  = (const float*)d_in[3];
    const float* W_pred = (const float*)d_in[4];
    const float* b_pred = (const float*)d_in[5];
    const float* W_out  = (const float*)d_in[6];
    const float* b_out  = (const float*)d_in[7];
    float* out = (float*)d_out;

    _Float16* enc_t  = (_Float16*)d_ws;                         // (B,T,EH)
    _Float16* dec_t  = enc_t  + (size_t)B_ * T_ * EH_;          // (B,U,PH)
    _Float16* wenc_f = dec_t  + (size_t)B_ * U_ * PH_;          // (JH,EH)
    _Float16* wpred_f= wenc_f + (size_t)JH_ * EH_;              // (JH,PH)
    _Float16* wout_f = wpred_f+ (size_t)JH_ * PH_;              // (48,JH) zero-padded
    _Float16* e_f    = wout_f + (size_t)48 * JH_;               // (B,T,JH)
    _Float16* p_f    = e_f    + (size_t)B_ * T_ * JH_;          // (B,U,JH)

    const int NE = 16 * 24 * B_, ND = 4 * 10 * B_;
    const int NW = (JH_ * EH_ + JH_ * PH_ + 48 * JH_ + 255) / 256;
    prep_kernel<<<dim3(NE + ND + NW), 256, 0, stream>>>(
        enc, dec, W_enc, W_pred, W_out, enc_t, dec_t, wenc_f, wpred_f, wout_f);

    const int We = (T_ / 32) * (JH_ / 32) * B_;
    const int Wp = (U_ / 32) * (JH_ / 32) * B_;
    proj_kernel<<<dim3((We + Wp) / 4), 256, 0, stream>>>(
        enc_t, dec_t, wenc_f, wpred_f, b_enc, b_pred, e_f, p_f);

    joint_kernel<<<dim3(T_ / 8, U_ / 32, B_), 256, 0, stream>>>(e_f, p_f, wout_f, b_out, out);
}